// Round 5
// baseline (1902.204 us; speedup 1.0000x reference)
//
#include <hip/hip_runtime.h>

#define NEG_INF_E (-1e9f)

typedef float floatx4 __attribute__((ext_vector_type(4)));

// ---------- helpers ----------
__device__ __forceinline__ float wave_sum(float v) {
#pragma unroll
    for (int off = 32; off > 0; off >>= 1)
        v += __shfl_xor(v, off, 64);
    return v;
}

__device__ __forceinline__ float wave_max(float v) {
#pragma unroll
    for (int off = 32; off > 0; off >>= 1)
        v = fmaxf(v, __shfl_xor(v, off, 64));
    return v;
}

__device__ __forceinline__ floatx4 ntload4(const float* p) {
    return __builtin_nontemporal_load((const floatx4*)p);
}

// ---------- control-block layout in d_ws ----------
// int ctl[128]:  [0]=ctr0  [1]=ctrA  [2]=ctrB  [3..34]=qcnt[32]
//                [35..66]=ecnt[32]   [67..98]=sbflag[32]
// float stats[64]: [0..31]=m_b  [32..63]=inv_b
// float q_ws[32768], e_ws[131072]
#define CTR0 0
#define CTRA 1
#define CTRB 2
#define QCNT 3
#define ECNT 35
#define SBF  67

// ---------- init: zero control block, stats, and context region of d_out ----------
__global__ void k_init(int* __restrict__ ctl, float* __restrict__ ctx) {
    const int tid = threadIdx.x;
    if (blockIdx.x == 0) {
        if (tid < 192) ctl[tid] = 0;  // 128 ints + 64 stat floats (bit-zero)
    }
    ctx[blockIdx.x * 1024 + tid] = 0.f;
}

// ---------- the mega kernel: linear -> energies -> softmax stats -> context ----------
// grid = 2048 x 256. Dynamic work claiming; per-b release/acquire dependencies.
__global__ void __launch_bounds__(256) k_mega(
        const float* __restrict__ query,    // (32,1024)
        const float* __restrict__ keys,     // (32,4096,1024)
        const float* __restrict__ values,   // (32,4096,1024)
        const int*   __restrict__ mask,     // (32,4096)
        const float* __restrict__ Wq,       // (1024,1024)
        int*   __restrict__ ctl,
        float* __restrict__ stats,          // m[32], inv[32]
        float* __restrict__ q_ws,           // 32768
        float* __restrict__ e_ws,           // 131072
        float* __restrict__ out) {          // [0,32768) ctx | [32768,...) attn
    __shared__ int s_u;
    __shared__ int s_old;
    __shared__ float red[4];
    __shared__ float a_s[64];

    const int tid  = threadIdx.x;
    const int lane = tid & 63;
    const int wv   = tid >> 6;  // 4 waves

    // ===== phase 0: q[b,k] = query[b,:] . Wq[k,:]  (512 units of 64 outputs) =====
    for (;;) {
        __syncthreads();
        if (tid == 0) s_u = atomicAdd(&ctl[CTR0], 1);
        __syncthreads();
        const int u = s_u;
        if (u >= 512) break;
        const int b = u >> 4;  // 16 units per b
        const floatx4* qr = (const floatx4*)(query + (size_t)b * 1024);
        floatx4 qv[4];
#pragma unroll
        for (int it = 0; it < 4; ++it) qv[it] = qr[lane + it * 64];
        const int k0 = u * 64 + wv * 16;  // this wave's 16 outputs
        for (int j = 0; j < 16; ++j) {
            const int kg = k0 + j;
            const floatx4* wr = (const floatx4*)(Wq + (size_t)(kg & 1023) * 1024);
            float acc = 0.f;
#pragma unroll
            for (int it = 0; it < 4; ++it) {
                const floatx4 w = wr[lane + it * 64];
                acc += qv[it].x * w.x + qv[it].y * w.y +
                       qv[it].z * w.z + qv[it].w * w.w;
            }
            acc = wave_sum(acc);
            if (lane == 0) q_ws[(size_t)b * 1024 + (kg & 1023)] = acc;
        }
        __syncthreads();
        if (tid == 0)
            __hip_atomic_fetch_add(&ctl[QCNT + b], 64, __ATOMIC_RELEASE,
                                   __HIP_MEMORY_SCOPE_AGENT);
    }

    // ===== phase A: energies (8192 units of 16 rows, b-major) =====
    for (;;) {
        __syncthreads();
        if (tid == 0) s_u = atomicAdd(&ctl[CTRA], 1);
        __syncthreads();
        const int u = s_u;
        if (u >= 8192) break;
        const int b = u >> 8;  // 256 units per b
        while (__hip_atomic_load(&ctl[QCNT + b], __ATOMIC_ACQUIRE,
                                 __HIP_MEMORY_SCOPE_AGENT) < 1024)
            __builtin_amdgcn_s_sleep(4);
        const floatx4* qr = (const floatx4*)(q_ws + (size_t)b * 1024);
        floatx4 qv[4];
#pragma unroll
        for (int it = 0; it < 4; ++it) qv[it] = qr[lane + it * 64];
        const int row0 = u * 16 + wv * 4;  // global row (b*4096+s)
#pragma unroll
        for (int i = 0; i < 4; ++i) {
            const int row = row0 + i;
            const float* kr = keys + (size_t)row * 1024;
            floatx4 kv[4];
#pragma unroll
            for (int it = 0; it < 4; ++it) kv[it] = ntload4(kr + (lane + it * 64) * 4);
            float acc = 0.f;
#pragma unroll
            for (int it = 0; it < 4; ++it)
                acc += kv[it].x * qv[it].x + kv[it].y * qv[it].y +
                       kv[it].z * qv[it].z + kv[it].w * qv[it].w;
            acc = wave_sum(acc);
            if (lane == 0) e_ws[row] = (mask[row] == 0) ? NEG_INF_E : acc;
        }
        __syncthreads();
        if (tid == 0)
            s_old = __hip_atomic_fetch_add(&ctl[ECNT + b], 16, __ATOMIC_ACQ_REL,
                                           __HIP_MEMORY_SCOPE_AGENT);
        __syncthreads();
        if (s_old + 16 == 4096) {
            // this block saw the last energies of b land -> compute softmax stats once
            const float* e = e_ws + (size_t)b * 4096;
            float ev[16];
            float m = -INFINITY;
#pragma unroll
            for (int i = 0; i < 16; ++i) {
                ev[i] = e[tid + i * 256];
                m = fmaxf(m, ev[i]);
            }
            m = wave_max(m);
            if (lane == 0) red[wv] = m;
            __syncthreads();
            const float bm = fmaxf(fmaxf(red[0], red[1]), fmaxf(red[2], red[3]));
            __syncthreads();
            float s = 0.f;
#pragma unroll
            for (int i = 0; i < 16; ++i) s += expf(ev[i] - bm);
            s = wave_sum(s);
            if (lane == 0) red[wv] = s;
            __syncthreads();
            if (tid == 0) {
                stats[b]      = bm;
                stats[32 + b] = 1.f / (red[0] + red[1] + red[2] + red[3]);
                __hip_atomic_store(&ctl[SBF + b], 1, __ATOMIC_RELEASE,
                                   __HIP_MEMORY_SCOPE_AGENT);
            }
        }
    }

    // ===== phase B: attn write + context accumulate (2048 units of 64 rows) =====
    for (;;) {
        __syncthreads();
        if (tid == 0) s_u = atomicAdd(&ctl[CTRB], 1);
        __syncthreads();
        const int u = s_u;
        if (u >= 2048) break;
        const int b  = u >> 6;  // 64 units per b
        const int s0 = (u & 63) * 64;
        while (__hip_atomic_load(&ctl[SBF + b], __ATOMIC_ACQUIRE,
                                 __HIP_MEMORY_SCOPE_AGENT) == 0)
            __builtin_amdgcn_s_sleep(8);
        const float bm  = stats[b];
        const float inv = stats[32 + b];
        if (tid < 64) {
            const float a = expf(e_ws[(size_t)b * 4096 + s0 + tid] - bm) * inv;
            a_s[tid] = a;
            __builtin_nontemporal_store(a, out + 32768 + (size_t)b * 4096 + s0 + tid);
        }
        __syncthreads();
        const float* vr = values + ((size_t)b * 4096 + s0) * 1024;
        floatx4 acc = (floatx4)0.f;
#pragma unroll 8
        for (int s2 = 0; s2 < 64; ++s2) {
            const float a = a_s[s2];
            const floatx4 v = ntload4(vr + (size_t)s2 * 1024 + tid * 4);
            acc.x += a * v.x;
            acc.y += a * v.y;
            acc.z += a * v.z;
            acc.w += a * v.w;
        }
        float* c = out + (size_t)b * 1024 + tid * 4;
        atomicAdd(c + 0, acc.x);
        atomicAdd(c + 1, acc.y);
        atomicAdd(c + 2, acc.z);
        atomicAdd(c + 3, acc.w);
    }
}

// ---------- fallback kernels (R3 path, used only if ws_size is too small) ----------
template <bool ZERO_CTX>
__global__ void k_linear(const float* __restrict__ query,
                         const float* __restrict__ Wq,
                         float* __restrict__ q_out,
                         float* __restrict__ ctx_zero) {
    const int lane = threadIdx.x & 63;
    const int wid  = blockIdx.x * 4 + (threadIdx.x >> 6);
    const int b = wid >> 10;
    const int k = wid & 1023;
    if (ZERO_CTX && blockIdx.x < 128)
        ctx_zero[blockIdx.x * 256 + threadIdx.x] = 0.f;
    const floatx4* qr = (const floatx4*)(query + (size_t)b * 1024);
    const floatx4* wr = (const floatx4*)(Wq + (size_t)k * 1024);
    float acc = 0.f;
#pragma unroll
    for (int it = 0; it < 4; ++it) {
        floatx4 a = qr[lane + it * 64];
        floatx4 w = wr[lane + it * 64];
        acc += a.x * w.x + a.y * w.y + a.z * w.z + a.w * w.w;
    }
    acc = wave_sum(acc);
    if (lane == 0) q_out[(size_t)b * 1024 + k] = acc;
}

__global__ void k_energy(const float* __restrict__ keys,
                         const float* __restrict__ q,
                         const int* __restrict__ mask,
                         float* __restrict__ energies) {
    const int lane = threadIdx.x & 63;
    const int wid  = blockIdx.x * 4 + (threadIdx.x >> 6);
    const int b = wid >> 12;
    const float* kr = keys + (size_t)wid * 1024;
    const floatx4* qr = (const floatx4*)(q + (size_t)b * 1024);
    floatx4 kv[4], qv[4];
#pragma unroll
    for (int it = 0; it < 4; ++it) kv[it] = ntload4(kr + (lane + it * 64) * 4);
#pragma unroll
    for (int it = 0; it < 4; ++it) qv[it] = qr[lane + it * 64];
    float acc = 0.f;
#pragma unroll
    for (int it = 0; it < 4; ++it)
        acc += kv[it].x * qv[it].x + kv[it].y * qv[it].y +
               kv[it].z * qv[it].z + kv[it].w * qv[it].w;
    acc = wave_sum(acc);
    if (lane == 0)
        energies[wid] = (mask[wid] == 0) ? NEG_INF_E : acc;
}

__global__ void k_softmax(float* __restrict__ d_out) {
    __shared__ float red[16];
    const int b = blockIdx.x;
    const int tid = threadIdx.x;
    const int lane = tid & 63;
    const int wv = tid >> 6;

    d_out[(size_t)b * 1024 + tid] = 0.f;

    float* e = d_out + 32768 + (size_t)b * 4096;
    float v[4];
    float m = -INFINITY;
#pragma unroll
    for (int i = 0; i < 4; ++i) {
        v[i] = e[tid + i * 1024];
        m = fmaxf(m, v[i]);
    }
    m = wave_max(m);
    if (lane == 0) red[wv] = m;
    __syncthreads();
    float bm = red[0];
#pragma unroll
    for (int i = 1; i < 16; ++i) bm = fmaxf(bm, red[i]);
    __syncthreads();

    float s = 0.f;
#pragma unroll
    for (int i = 0; i < 4; ++i) {
        v[i] = expf(v[i] - bm);
        s += v[i];
    }
    s = wave_sum(s);
    if (lane == 0) red[wv] = s;
    __syncthreads();
    float bs = 0.f;
#pragma unroll
    for (int i = 0; i < 16; ++i) bs += red[i];
    const float inv = 1.f / bs;
#pragma unroll
    for (int i = 0; i < 4; ++i) e[tid + i * 1024] = v[i] * inv;
}

__global__ void k_context(const float* __restrict__ values,
                          const float* __restrict__ attn,
                          float* __restrict__ context) {
    __shared__ float a_s[128];
    const int b = blockIdx.x;
    const int s0 = blockIdx.y * 128;
    const int tid = threadIdx.x;

    if (tid < 128) a_s[tid] = attn[(size_t)b * 4096 + s0 + tid];
    __syncthreads();

    const float* vr = values + ((size_t)b * 4096 + s0) * 1024;
    floatx4 acc = (floatx4)0.f;
#pragma unroll 8
    for (int s = 0; s < 128; ++s) {
        const float a = a_s[s];
        const floatx4 v = ntload4(vr + (size_t)s * 1024 + tid * 4);
        acc.x += a * v.x;
        acc.y += a * v.y;
        acc.z += a * v.z;
        acc.w += a * v.w;
    }
    float* c = context + (size_t)b * 1024 + tid * 4;
    atomicAdd(c + 0, acc.x);
    atomicAdd(c + 1, acc.y);
    atomicAdd(c + 2, acc.z);
    atomicAdd(c + 3, acc.w);
}

// ---------- launch ----------
extern "C" void kernel_launch(void* const* d_in, const int* in_sizes, int n_in,
                              void* d_out, int out_size, void* d_ws, size_t ws_size,
                              hipStream_t stream) {
    const float* query  = (const float*)d_in[0];  // (32, 1024)
    const float* keys   = (const float*)d_in[1];  // (32, 4096, 1024)
    const float* values = (const float*)d_in[2];  // (32, 4096, 1024)
    const int*   mask   = (const int*)d_in[3];    // (32, 4096)
    const float* Wq     = (const float*)d_in[4];  // (1024, 1024)
    float* out = (float*)d_out;                   // [0,32768) ctx | [32768,163840) attn

    // mega path needs: 128 ints + 64 stat floats + 32768 q + 131072 energies
    const size_t need = (size_t)(128 + 64 + 32768 + 131072) * 4;
    if (ws_size >= need) {
        int*   ctl   = (int*)d_ws;
        float* stats = (float*)d_ws + 128;
        float* q_ws  = (float*)d_ws + 192;
        float* e_ws  = q_ws + 32768;
        k_init<<<32, 1024, 0, stream>>>(ctl, out);
        k_mega<<<2048, 256, 0, stream>>>(query, keys, values, mask, Wq,
                                         ctl, stats, q_ws, e_ws, out);
    } else {
        float* q_tmp    = out;          // context region doubles as q scratch
        float* energies = out + 32768;  // attn region holds raw energies
        k_linear<false><<<8192, 256, 0, stream>>>(query, Wq, q_tmp, out);
        k_energy<<<32768, 256, 0, stream>>>(keys, q_tmp, mask, energies);
        k_softmax<<<32, 1024, 0, stream>>>(out);
        k_context<<<dim3(32, 32), 256, 0, stream>>>(values, energies, out);
    }
}

// Round 6
// 185.734 us; speedup vs baseline: 10.2415x; 10.2415x over previous
//
#include <hip/hip_runtime.h>

#define NEG_INF_E (-1e9f)

typedef float floatx4 __attribute__((ext_vector_type(4)));

// ---------- helpers ----------
__device__ __forceinline__ float wave_sum(float v) {
#pragma unroll
    for (int off = 32; off > 0; off >>= 1)
        v += __shfl_xor(v, off, 64);
    return v;
}

__device__ __forceinline__ float wave_max(float v) {
#pragma unroll
    for (int off = 32; off > 0; off >>= 1)
        v = fmaxf(v, __shfl_xor(v, off, 64));
    return v;
}

__device__ __forceinline__ floatx4 ntload4(const float* p) {
    return __builtin_nontemporal_load((const floatx4*)p);
}

// ---------- kernel 0: q[b,k] = sum_q query[b,q] * W_q[k,q] ----------
// one wave per output element. ZERO_CTX: blocks 0..127 also zero the context
// region of d_out (used by the fused path, where softmax no longer does it).
template <bool ZERO_CTX>
__global__ void k_linear(const float* __restrict__ query,
                         const float* __restrict__ Wq,
                         float* __restrict__ q_out,
                         float* __restrict__ ctx_zero) {
    const int lane = threadIdx.x & 63;
    const int wid  = blockIdx.x * 4 + (threadIdx.x >> 6);  // 0..32767
    const int b = wid >> 10;
    const int k = wid & 1023;
    if (ZERO_CTX && blockIdx.x < 128)
        ctx_zero[blockIdx.x * 256 + threadIdx.x] = 0.f;
    const floatx4* qr = (const floatx4*)(query + (size_t)b * 1024);
    const floatx4* wr = (const floatx4*)(Wq + (size_t)k * 1024);
    float acc = 0.f;
#pragma unroll
    for (int it = 0; it < 4; ++it) {
        floatx4 a = qr[lane + it * 64];
        floatx4 w = wr[lane + it * 64];
        acc += a.x * w.x + a.y * w.y + a.z * w.z + a.w * w.w;
    }
    acc = wave_sum(acc);
    if (lane == 0) q_out[(size_t)b * 1024 + k] = acc;
}

// ---------- kernel 1: energies[b,s] = dot(keys[b,s,:], q[b,:]) with mask ----------
// one wave per (b,s) row; keys streamed nontemporally (no reuse), q from cache
__global__ void k_energy(const float* __restrict__ keys,
                         const float* __restrict__ q,
                         const int* __restrict__ mask,
                         float* __restrict__ energies) {
    const int lane = threadIdx.x & 63;
    const int wid  = blockIdx.x * 4 + (threadIdx.x >> 6);  // 0..131071 == b*4096+s
    const int b = wid >> 12;
    const float* kr = keys + (size_t)wid * 1024;
    const floatx4* qr = (const floatx4*)(q + (size_t)b * 1024);
    floatx4 kv[4], qv[4];
#pragma unroll
    for (int it = 0; it < 4; ++it) kv[it] = ntload4(kr + (lane + it * 64) * 4);
#pragma unroll
    for (int it = 0; it < 4; ++it) qv[it] = qr[lane + it * 64];
    float acc = 0.f;
#pragma unroll
    for (int it = 0; it < 4; ++it) {
        acc += kv[it].x * qv[it].x + kv[it].y * qv[it].y +
               kv[it].z * qv[it].z + kv[it].w * qv[it].w;
    }
    acc = wave_sum(acc);
    if (lane == 0)
        energies[wid] = (mask[wid] == 0) ? NEG_INF_E : acc;
}

// ---------- fused kernel 2: softmax stats + attn write + context accumulate ----------
// grid = (32 b, 32 chunks of 128 rows), block = 256 threads.
// Each block redundantly computes row max / Z from the L2-resident energies row
// (deterministic: same data, same reduction order per b), normalizes and writes
// its own 128 attn values, then streams its values chunk.
__global__ void k_context_fused(const float* __restrict__ values,
                                const float* __restrict__ energies,
                                float* __restrict__ out) {  // [0,32768) ctx | [32768,...) attn
    __shared__ float red[4];
    __shared__ float a_s[128];
    const int b = blockIdx.x;
    const int s0 = blockIdx.y * 128;
    const int tid = threadIdx.x;
    const int lane = tid & 63;
    const int wv = tid >> 6;  // 4 waves

    const float* e = energies + (size_t)b * 4096;
    float ev[16];
    float m = -INFINITY;
#pragma unroll
    for (int i = 0; i < 16; ++i) {
        ev[i] = e[tid + i * 256];
        m = fmaxf(m, ev[i]);
    }
    m = wave_max(m);
    if (lane == 0) red[wv] = m;
    __syncthreads();
    const float bm = fmaxf(fmaxf(red[0], red[1]), fmaxf(red[2], red[3]));
    __syncthreads();

    float s = 0.f;
#pragma unroll
    for (int i = 0; i < 16; ++i) s += expf(ev[i] - bm);
    s = wave_sum(s);
    if (lane == 0) red[wv] = s;
    __syncthreads();
    const float inv = 1.f / (red[0] + red[1] + red[2] + red[3]);

    if (tid < 128) {
        const float a = expf(e[s0 + tid] - bm) * inv;
        a_s[tid] = a;
        __builtin_nontemporal_store(a, out + 32768 + (size_t)b * 4096 + s0 + tid);
    }
    __syncthreads();

    const float* vr = values + ((size_t)b * 4096 + s0) * 1024;
    floatx4 acc = (floatx4)0.f;
#pragma unroll 8
    for (int s2 = 0; s2 < 128; ++s2) {
        const float a = a_s[s2];
        const floatx4 v = ntload4(vr + (size_t)s2 * 1024 + tid * 4);
        acc.x += a * v.x;
        acc.y += a * v.y;
        acc.z += a * v.z;
        acc.w += a * v.w;
    }
    float* c = out + (size_t)b * 1024 + tid * 4;
    atomicAdd(c + 0, acc.x);
    atomicAdd(c + 1, acc.y);
    atomicAdd(c + 2, acc.z);
    atomicAdd(c + 3, acc.w);
}

// ---------- fallback kernels (used only if ws_size is too small) ----------
__global__ void k_softmax(float* __restrict__ d_out) {
    __shared__ float red[16];
    const int b = blockIdx.x;
    const int tid = threadIdx.x;
    const int lane = tid & 63;
    const int wv = tid >> 6;

    d_out[(size_t)b * 1024 + tid] = 0.f;

    float* e = d_out + 32768 + (size_t)b * 4096;
    float v[4];
    float m = -INFINITY;
#pragma unroll
    for (int i = 0; i < 4; ++i) {
        v[i] = e[tid + i * 1024];
        m = fmaxf(m, v[i]);
    }
    m = wave_max(m);
    if (lane == 0) red[wv] = m;
    __syncthreads();
    float bm = red[0];
#pragma unroll
    for (int i = 1; i < 16; ++i) bm = fmaxf(bm, red[i]);
    __syncthreads();

    float s = 0.f;
#pragma unroll
    for (int i = 0; i < 4; ++i) {
        v[i] = expf(v[i] - bm);
        s += v[i];
    }
    s = wave_sum(s);
    if (lane == 0) red[wv] = s;
    __syncthreads();
    float bs = 0.f;
#pragma unroll
    for (int i = 0; i < 16; ++i) bs += red[i];
    const float inv = 1.f / bs;
#pragma unroll
    for (int i = 0; i < 4; ++i) e[tid + i * 1024] = v[i] * inv;
}

__global__ void k_context(const float* __restrict__ values,
                          const float* __restrict__ attn,
                          float* __restrict__ context) {
    __shared__ float a_s[128];
    const int b = blockIdx.x;
    const int s0 = blockIdx.y * 128;
    const int tid = threadIdx.x;

    if (tid < 128) a_s[tid] = attn[(size_t)b * 4096 + s0 + tid];
    __syncthreads();

    const float* vr = values + ((size_t)b * 4096 + s0) * 1024;
    floatx4 acc = (floatx4)0.f;
#pragma unroll 8
    for (int s = 0; s < 128; ++s) {
        const float a = a_s[s];
        const floatx4 v = ntload4(vr + (size_t)s * 1024 + tid * 4);
        acc.x += a * v.x;
        acc.y += a * v.y;
        acc.z += a * v.z;
        acc.w += a * v.w;
    }
    float* c = context + (size_t)b * 1024 + tid * 4;
    atomicAdd(c + 0, acc.x);
    atomicAdd(c + 1, acc.y);
    atomicAdd(c + 2, acc.z);
    atomicAdd(c + 3, acc.w);
}

// ---------- launch ----------
extern "C" void kernel_launch(void* const* d_in, const int* in_sizes, int n_in,
                              void* d_out, int out_size, void* d_ws, size_t ws_size,
                              hipStream_t stream) {
    const float* query  = (const float*)d_in[0];  // (32, 1024)
    const float* keys   = (const float*)d_in[1];  // (32, 4096, 1024)
    const float* values = (const float*)d_in[2];  // (32, 4096, 1024)
    const int*   mask   = (const int*)d_in[3];    // (32, 4096)
    const float* Wq     = (const float*)d_in[4];  // (1024, 1024)
    float* out = (float*)d_out;                   // [0,32768) context | [32768,163840) attn

    // need 32768 (q) + 131072 (energies) floats = 640 KB of scratch
    if (ws_size >= (32768 + 131072) * sizeof(float)) {
        float* q_tmp    = (float*)d_ws;
        float* energies = (float*)d_ws + 32768;
        k_linear<true><<<8192, 256, 0, stream>>>(query, Wq, q_tmp, out);
        k_energy<<<32768, 256, 0, stream>>>(keys, q_tmp, mask, energies);
        k_context_fused<<<dim3(32, 32), 256, 0, stream>>>(values, energies, out);
    } else {
        float* q_tmp    = out;          // context region doubles as q scratch
        float* energies = out + 32768;  // attn region holds raw energies
        k_linear<false><<<8192, 256, 0, stream>>>(query, Wq, q_tmp, out);
        k_energy<<<32768, 256, 0, stream>>>(keys, q_tmp, mask, energies);
        k_softmax<<<32, 1024, 0, stream>>>(out);
        k_context<<<dim3(32, 32), 256, 0, stream>>>(values, energies, out);
    }
}